// Round 2
// baseline (791.675 us; speedup 1.0000x reference)
//
#include <hip/hip_runtime.h>
#include <hip/hip_bf16.h>

#define CCH 128
#define HGT 256
#define WID 256
#define HW  65536

// ws layout:
//   floats [0,512)    sum_h (4*128)
//   floats [512,1024) sum_v
//   floats [1024,1032) wgate (4*2)
//   byte 32768:       hbuf bf16 (4*128*65536)
//   then              vbuf bf16
// total ws needed = 32768 + 2*67108864 = 134,250,496 bytes

__global__ __launch_bounds__(256) void prep_kernel(float* __restrict__ sums) {
  int t = threadIdx.x;
  for (int i = t; i < 1032; i += 256) sums[i] = 0.f;  // sum_h, sum_v, wgate
}

// one block per (b,c,y) row: exact two-stage horizontal conv.
// stage1: s1(q) = sum_i h1[i]*xpad(q+i-2), q in [0,255], ZERO outside (reference
// zero-pads the intermediate). stage2: h(p) = sum_j h2[j]*s1pad(p+3j-9).
__global__ __launch_bounds__(256) void convh_kernel(
    const float* __restrict__ x, const float* __restrict__ h1w,
    const float* __restrict__ h2w,
    __hip_bfloat16* __restrict__ hbuf, float* __restrict__ sum_h) {
  int bid = blockIdx.x;        // (b*C + c)*256 + y
  int y = bid & 255;
  int bc = bid >> 8;
  int c = bc & (CCH - 1);
  int t = threadIdx.x;
  __shared__ float row[WID + 4];    // xpad(-2..257)
  __shared__ float tmp[WID + 18];   // s1pad(-9..264)
  __shared__ float red[4];
  const float* xr = x + (size_t)bc * HW + (size_t)y * WID;
  row[t + 2] = xr[t];
  if (t < 2) { row[t] = 0.f; row[WID + 2 + t] = 0.f; }
  if (t < 9) { tmp[t] = 0.f; tmp[WID + 9 + t] = 0.f; }
  float h1c[5], h2c[7];
#pragma unroll
  for (int i = 0; i < 5; ++i) h1c[i] = h1w[c * 5 + i];
#pragma unroll
  for (int j = 0; j < 7; ++j) h2c[j] = h2w[c * 7 + j];
  __syncthreads();
  float s1 = 0.f;
#pragma unroll
  for (int i = 0; i < 5; ++i) s1 = fmaf(row[t + i], h1c[i], s1);
  tmp[t + 9] = s1;
  __syncthreads();
  float s = 0.f;
#pragma unroll
  for (int j = 0; j < 7; ++j) s = fmaf(tmp[t + 3 * j], h2c[j], s);
  hbuf[(size_t)bc * HW + (size_t)y * WID + t] = __float2bfloat16(s);
  float r = s;
#pragma unroll
  for (int off = 32; off > 0; off >>= 1) r += __shfl_down(r, off);
  if ((t & 63) == 0) red[t >> 6] = r;
  __syncthreads();
  if (t == 0) atomicAdd(&sum_h[bc], red[0] + red[1] + red[2] + red[3]);
}

// one block per (b,c,y-half): exact two-stage vertical conv with register
// sliding windows. s1 ring holds 19 zero-padded intermediate values.
__global__ __launch_bounds__(256) void convv_kernel(
    const float* __restrict__ x, const float* __restrict__ v1w,
    const float* __restrict__ v2w,
    __hip_bfloat16* __restrict__ vbuf, float* __restrict__ sum_v) {
  int bid = blockIdx.x;        // (b*C + c)*2 + half
  int half = bid & 1;
  int bc = bid >> 1;
  int c = bc & (CCH - 1);
  int t = threadIdx.x;         // column
  int y0 = half * 128;
  const float* xp = x + (size_t)bc * HW;
  float v1c[5], v2c[7];
#pragma unroll
  for (int i = 0; i < 5; ++i) v1c[i] = v1w[c * 5 + i];
#pragma unroll
  for (int j = 0; j < 7; ++j) v2c[j] = v2w[c * 7 + j];

  // xloc[m] = xpad(y0-11+m), m in [0,22]
  float xloc[23];
#pragma unroll
  for (int m = 0; m < 23; ++m) {
    int yy = y0 - 11 + m;
    xloc[m] = (yy >= 0 && yy < HGT) ? xp[(size_t)yy * WID + t] : 0.f;
  }
  // s1w[m] = s1pad(y0-9+m), m in [0,18]; s1(q)=sum_i v1[i]*xpad(q-2+i), zero for q outside
  float s1w[19];
#pragma unroll
  for (int m = 0; m < 19; ++m) {
    int q = y0 - 9 + m;
    float v = 0.f;
    if (q >= 0 && q < HGT) {
#pragma unroll
      for (int i = 0; i < 5; ++i) v = fmaf(xloc[m + i], v1c[i], v);
    }
    s1w[m] = v;
  }
  // xw[i] = xpad(y+8+i), i in [0,4] (for producing s1(y+10))
  float xw[5];
#pragma unroll
  for (int i = 0; i < 5; ++i) {
    int yy = y0 + 8 + i;
    xw[i] = (yy >= 0 && yy < HGT) ? xp[(size_t)yy * WID + t] : 0.f;
  }

  __hip_bfloat16* vp = vbuf + (size_t)bc * HW;
  float acc = 0.f;
  for (int y = y0; y < y0 + 128; ++y) {
    float s = 0.f;
#pragma unroll
    for (int j = 0; j < 7; ++j) s = fmaf(s1w[3 * j], v2c[j], s);
    vp[(size_t)y * WID + t] = __float2bfloat16(s);
    acc += s;
#pragma unroll
    for (int m = 0; m < 18; ++m) s1w[m] = s1w[m + 1];
    int q = y + 10;
    float ns = 0.f;
    if (q < HGT) {
#pragma unroll
      for (int i = 0; i < 5; ++i) ns = fmaf(xw[i], v1c[i], ns);
    }
    s1w[18] = ns;
#pragma unroll
    for (int i = 0; i < 4; ++i) xw[i] = xw[i + 1];
    int yy = y + 13;
    xw[4] = (yy < HGT) ? xp[(size_t)yy * WID + t] : 0.f;
  }
  __shared__ float red[4];
#pragma unroll
  for (int off = 32; off > 0; off >>= 1) acc += __shfl_down(acc, off);
  if ((t & 63) == 0) red[t >> 6] = acc;
  __syncthreads();
  if (t == 0) atomicAdd(&sum_v[bc], red[0] + red[1] + red[2] + red[3]);
}

// single block: pooled -> g1 -> SiLU -> g2 -> softmax
__global__ __launch_bounds__(128) void gate_kernel(
    const float* __restrict__ sum_h, const float* __restrict__ sum_v,
    const float* __restrict__ g1w, const float* __restrict__ g2w,
    const float* __restrict__ g2b, float* __restrict__ wgate) {
  int t = threadIdx.x;
  __shared__ float gs[4][32];
  int b = t >> 5, r = t & 31;
  {
    float acc = 0.f;
    const float inv = 1.f / 65536.f;
    for (int k = 0; k < 128; ++k)
      acc = fmaf(sum_h[b * 128 + k] * inv, g1w[r * 256 + k], acc);
    for (int k = 0; k < 128; ++k)
      acc = fmaf(sum_v[b * 128 + k] * inv, g1w[r * 256 + 128 + k], acc);
    float sig = 1.f / (1.f + expf(-acc));
    gs[b][r] = acc * sig;
  }
  __syncthreads();
  if (t < 4) {
    float t0 = g2b[0], t1 = g2b[1];
    for (int rr = 0; rr < 32; ++rr) {
      t0 = fmaf(gs[t][rr], g2w[rr], t0);
      t1 = fmaf(gs[t][rr], g2w[32 + rr], t1);
    }
    float mx = fmaxf(t0, t1);
    float e0 = expf(t0 - mx), e1 = expf(t1 - mx);
    float inv = 1.f / (e0 + e1);
    wgate[t * 2 + 0] = e0 * inv;
    wgate[t * 2 + 1] = e1 * inv;
  }
}

__device__ __forceinline__ float bf2f(unsigned short u) {
  return __uint_as_float(((unsigned)u) << 16);
}

// one block per (b, y, x-half): 128-channel x 128-pixel tile.
// attn[o,p] = fuse_b[o] + sum_c Wt[c,o]*a[c,p];  out = x*(0.5+0.5*attn)
__global__ __launch_bounds__(256) void fuse_kernel(
    const float* __restrict__ x, const __hip_bfloat16* __restrict__ hbuf,
    const __hip_bfloat16* __restrict__ vbuf, const float* __restrict__ fuse_w,
    const float* __restrict__ fuse_b, const float* __restrict__ wgate,
    float* __restrict__ out) {
  __shared__ unsigned short aS[128 * 128];  // a[c][p] bf16
  __shared__ unsigned short wS[128 * 128];  // Wt[c][o] bf16, o column swizzled
  int bid = blockIdx.x;        // (b*256 + y)*2 + half
  int half = bid & 1;
  int y = (bid >> 1) & 255;
  int b = bid >> 9;
  int t = threadIdx.x;
  float wh = wgate[b * 2], wv = wgate[b * 2 + 1];

  // stage Wt (swizzled column: col = (o + 8*(c&15)) & 127 to dodge bank conflicts)
  for (int q = t; q < 16384; q += 256) {
    int o = q >> 7, cc = q & 127;
    int col = (o + 8 * (cc & 15)) & 127;
    wS[cc * 128 + col] = __bfloat16_as_ushort(__float2bfloat16(fuse_w[q]));
  }
  // stage a = wh*h + wv*v
  size_t base = (size_t)b * CCH * HW + (size_t)y * WID + (size_t)half * 128;
  for (int q = t; q < 16384; q += 256) {
    int cc = q >> 7, p = q & 127;
    size_t gi = base + (size_t)cc * HW + p;
    float hv = __bfloat162float(hbuf[gi]);
    float vv = __bfloat162float(vbuf[gi]);
    aS[cc * 128 + p] = __bfloat16_as_ushort(__float2bfloat16(fmaf(wh, hv, wv * vv)));
  }
  __syncthreads();

  int o0 = (t >> 4) * 8;
  int p0 = (t & 15) * 8;
  float acc[8][8];
#pragma unroll
  for (int i = 0; i < 8; ++i)
#pragma unroll
    for (int j = 0; j < 8; ++j) acc[i][j] = 0.f;

  for (int cc = 0; cc < 128; ++cc) {
    int wbase = cc * 128 + ((o0 + 8 * (cc & 15)) & 127);
    int abase = cc * 128 + p0;
    ushort4 w0 = *(const ushort4*)&wS[wbase];
    ushort4 w1 = *(const ushort4*)&wS[wbase + 4];
    ushort4 a0 = *(const ushort4*)&aS[abase];
    ushort4 a1 = *(const ushort4*)&aS[abase + 4];
    float wr[8] = {bf2f(w0.x), bf2f(w0.y), bf2f(w0.z), bf2f(w0.w),
                   bf2f(w1.x), bf2f(w1.y), bf2f(w1.z), bf2f(w1.w)};
    float ar[8] = {bf2f(a0.x), bf2f(a0.y), bf2f(a0.z), bf2f(a0.w),
                   bf2f(a1.x), bf2f(a1.y), bf2f(a1.z), bf2f(a1.w)};
#pragma unroll
    for (int i = 0; i < 8; ++i)
#pragma unroll
      for (int j = 0; j < 8; ++j) acc[i][j] = fmaf(wr[i], ar[j], acc[i][j]);
  }

#pragma unroll
  for (int i = 0; i < 8; ++i) {
    int o = o0 + i;
    float fb = fuse_b[o];
    size_t gb = base + (size_t)o * HW + p0;
#pragma unroll
    for (int j = 0; j < 8; ++j) {
      float attn = fb + acc[i][j];
      float xv = x[gb + j];
      out[gb + j] = xv * fmaf(0.5f, attn, 0.5f);
    }
  }
}

extern "C" void kernel_launch(void* const* d_in, const int* in_sizes, int n_in,
                              void* d_out, int out_size, void* d_ws, size_t ws_size,
                              hipStream_t stream) {
  const float* x      = (const float*)d_in[0];
  const float* h1w    = (const float*)d_in[1];
  const float* h2w    = (const float*)d_in[2];
  const float* v1w    = (const float*)d_in[3];
  const float* v2w    = (const float*)d_in[4];
  const float* g1w    = (const float*)d_in[5];
  const float* g2w    = (const float*)d_in[6];
  const float* g2b    = (const float*)d_in[7];
  const float* fusew  = (const float*)d_in[8];
  const float* fuseb  = (const float*)d_in[9];
  float* out = (float*)d_out;

  float* sums  = (float*)d_ws;       // sum_h(512), sum_v(512), wgate(8)
  float* sum_h = sums;
  float* sum_v = sums + 512;
  float* wgate = sums + 1024;
  __hip_bfloat16* hbuf = (__hip_bfloat16*)((char*)d_ws + 32768);
  __hip_bfloat16* vbuf = hbuf + (size_t)4 * CCH * HW;

  prep_kernel<<<1, 256, 0, stream>>>(sums);
  convh_kernel<<<4 * CCH * HGT, 256, 0, stream>>>(x, h1w, h2w, hbuf, sum_h);
  convv_kernel<<<4 * CCH * 2, 256, 0, stream>>>(x, v1w, v2w, vbuf, sum_v);
  gate_kernel<<<1, 128, 0, stream>>>(sum_h, sum_v, g1w, g2w, g2b, wgate);
  fuse_kernel<<<4 * HGT * 2, 256, 0, stream>>>(x, hbuf, vbuf, fusew, fuseb, wgate, out);
}

// Round 3
// 519.032 us; speedup vs baseline: 1.5253x; 1.5253x over previous
//
#include <hip/hip_runtime.h>
#include <hip/hip_bf16.h>

#define CCH 128
#define HGT 256
#define WID 256
#define HW  65536

// ws layout:
//   floats [0,512)    sum_h (4*128)
//   floats [512,1024) sum_v
//   floats [1024,1032) wgate (4*2)
//   byte 32768:       hbuf bf16 (4*128*65536)
//   then              vbuf bf16
// total ws needed = 32768 + 2*67108864 = 134,250,496 bytes

__global__ __launch_bounds__(256) void prep_kernel(float* __restrict__ sums) {
  int t = threadIdx.x;
  for (int i = t; i < 1032; i += 256) sums[i] = 0.f;  // sum_h, sum_v, wgate
}

// one block per (b,c,ytile16): exact two-stage horizontal conv on a 16-row tile.
// stage1: s1(q) = sum_i h1[i]*xpad(q+i-2), q in [0,255], ZERO outside (reference
// zero-pads the intermediate). stage2: h(p) = sum_j h2[j]*s1pad(p+3j-9).
// LDS layout: xr rows of 260 (2 zero pad each side), tmp rows of 276 (9 each side).
// Compute mapping thread<->column: stage1 reads stride-1 (conflict-free),
// stage2 reads stride-3 (2 lanes/bank = free). Global loads float4.
__global__ __launch_bounds__(256) void convh_kernel(
    const float* __restrict__ x, const float* __restrict__ h1w,
    const float* __restrict__ h2w,
    __hip_bfloat16* __restrict__ hbuf, float* __restrict__ sum_h) {
  __shared__ float xr[16 * 260];
  __shared__ float tmp[16 * 276];
  __shared__ float red[4];
  int bid = blockIdx.x;          // (b*C + c)*16 + ytile
  int y0 = (bid & 15) * 16;
  int bc = bid >> 4;
  int c = bc & (CCH - 1);
  int t = threadIdx.x;
  int rowg = t >> 6;             // 0..3 (wave id)
  int c4 = (t & 63) * 4;

  // zero pads: xr cols {0,1,258,259}, tmp cols {0..8, 265..273} for all 16 rows
  if (t < 64) {
    int r = t >> 2, k = t & 3;
    int col = (k < 2) ? k : (256 + k);
    xr[r * 260 + col] = 0.f;
  }
  for (int i = t; i < 288; i += 256) {
    int r = i / 18, k = i - r * 18;
    int col = (k < 9) ? k : (256 + k);
    tmp[r * 276 + col] = 0.f;
  }

  // stage 16 rows: wave w loads rows {w, w+4, w+8, w+12} as float4 per lane
  const float* xg = x + (size_t)bc * HW + (size_t)y0 * WID;
#pragma unroll
  for (int k = 0; k < 4; ++k) {
    int r = 4 * k + rowg;
    float4 v = *(const float4*)(xg + (size_t)r * WID + c4);
    *(float2*)&xr[r * 260 + 2 + c4] = make_float2(v.x, v.y);
    *(float2*)&xr[r * 260 + 4 + c4] = make_float2(v.z, v.w);
  }
  float h1c[5], h2c[7];
#pragma unroll
  for (int i = 0; i < 5; ++i) h1c[i] = h1w[c * 5 + i];
#pragma unroll
  for (int j = 0; j < 7; ++j) h2c[j] = h2w[c * 7 + j];
  __syncthreads();

  // stage1: col t of all 16 rows
#pragma unroll
  for (int r = 0; r < 16; ++r) {
    float s1 = 0.f;
#pragma unroll
    for (int i = 0; i < 5; ++i) s1 = fmaf(xr[r * 260 + t + i], h1c[i], s1);
    tmp[r * 276 + 9 + t] = s1;
  }
  __syncthreads();

  // stage2 + store + rowsum accumulation
  __hip_bfloat16* hg = hbuf + (size_t)bc * HW + (size_t)y0 * WID + t;
  float acc = 0.f;
#pragma unroll
  for (int r = 0; r < 16; ++r) {
    float s = 0.f;
#pragma unroll
    for (int j = 0; j < 7; ++j) s = fmaf(tmp[r * 276 + t + 3 * j], h2c[j], s);
    hg[(size_t)r * WID] = __float2bfloat16(s);
    acc += s;
  }
#pragma unroll
  for (int off = 32; off > 0; off >>= 1) acc += __shfl_down(acc, off);
  if ((t & 63) == 0) red[t >> 6] = acc;
  __syncthreads();
  if (t == 0) atomicAdd(&sum_h[bc], red[0] + red[1] + red[2] + red[3]);
}

// one block per (b,c,y-half): exact two-stage vertical conv with register
// sliding windows. s1 ring holds 19 zero-padded intermediate values.
__global__ __launch_bounds__(256) void convv_kernel(
    const float* __restrict__ x, const float* __restrict__ v1w,
    const float* __restrict__ v2w,
    __hip_bfloat16* __restrict__ vbuf, float* __restrict__ sum_v) {
  int bid = blockIdx.x;        // (b*C + c)*2 + half
  int half = bid & 1;
  int bc = bid >> 1;
  int c = bc & (CCH - 1);
  int t = threadIdx.x;         // column
  int y0 = half * 128;
  const float* xp = x + (size_t)bc * HW;
  float v1c[5], v2c[7];
#pragma unroll
  for (int i = 0; i < 5; ++i) v1c[i] = v1w[c * 5 + i];
#pragma unroll
  for (int j = 0; j < 7; ++j) v2c[j] = v2w[c * 7 + j];

  // xloc[m] = xpad(y0-11+m), m in [0,22]
  float xloc[23];
#pragma unroll
  for (int m = 0; m < 23; ++m) {
    int yy = y0 - 11 + m;
    xloc[m] = (yy >= 0 && yy < HGT) ? xp[(size_t)yy * WID + t] : 0.f;
  }
  // s1w[m] = s1pad(y0-9+m), m in [0,18]; s1(q)=sum_i v1[i]*xpad(q-2+i), zero for q outside
  float s1w[19];
#pragma unroll
  for (int m = 0; m < 19; ++m) {
    int q = y0 - 9 + m;
    float v = 0.f;
    if (q >= 0 && q < HGT) {
#pragma unroll
      for (int i = 0; i < 5; ++i) v = fmaf(xloc[m + i], v1c[i], v);
    }
    s1w[m] = v;
  }
  // xw[i] = xpad(y+8+i), i in [0,4] (for producing s1(y+10))
  float xw[5];
#pragma unroll
  for (int i = 0; i < 5; ++i) {
    int yy = y0 + 8 + i;
    xw[i] = (yy >= 0 && yy < HGT) ? xp[(size_t)yy * WID + t] : 0.f;
  }

  __hip_bfloat16* vp = vbuf + (size_t)bc * HW;
  float acc = 0.f;
  for (int y = y0; y < y0 + 128; ++y) {
    float s = 0.f;
#pragma unroll
    for (int j = 0; j < 7; ++j) s = fmaf(s1w[3 * j], v2c[j], s);
    vp[(size_t)y * WID + t] = __float2bfloat16(s);
    acc += s;
#pragma unroll
    for (int m = 0; m < 18; ++m) s1w[m] = s1w[m + 1];
    int q = y + 10;
    float ns = 0.f;
    if (q < HGT) {
#pragma unroll
      for (int i = 0; i < 5; ++i) ns = fmaf(xw[i], v1c[i], ns);
    }
    s1w[18] = ns;
#pragma unroll
    for (int i = 0; i < 4; ++i) xw[i] = xw[i + 1];
    int yy = y + 13;
    xw[4] = (yy < HGT) ? xp[(size_t)yy * WID + t] : 0.f;
  }
  __shared__ float red[4];
#pragma unroll
  for (int off = 32; off > 0; off >>= 1) acc += __shfl_down(acc, off);
  if ((t & 63) == 0) red[t >> 6] = acc;
  __syncthreads();
  if (t == 0) atomicAdd(&sum_v[bc], red[0] + red[1] + red[2] + red[3]);
}

// single block: pooled -> g1 -> SiLU -> g2 -> softmax
__global__ __launch_bounds__(128) void gate_kernel(
    const float* __restrict__ sum_h, const float* __restrict__ sum_v,
    const float* __restrict__ g1w, const float* __restrict__ g2w,
    const float* __restrict__ g2b, float* __restrict__ wgate) {
  int t = threadIdx.x;
  __shared__ float gs[4][32];
  int b = t >> 5, r = t & 31;
  {
    float acc = 0.f;
    const float inv = 1.f / 65536.f;
    for (int k = 0; k < 128; ++k)
      acc = fmaf(sum_h[b * 128 + k] * inv, g1w[r * 256 + k], acc);
    for (int k = 0; k < 128; ++k)
      acc = fmaf(sum_v[b * 128 + k] * inv, g1w[r * 256 + 128 + k], acc);
    float sig = 1.f / (1.f + expf(-acc));
    gs[b][r] = acc * sig;
  }
  __syncthreads();
  if (t < 4) {
    float t0 = g2b[0], t1 = g2b[1];
    for (int rr = 0; rr < 32; ++rr) {
      t0 = fmaf(gs[t][rr], g2w[rr], t0);
      t1 = fmaf(gs[t][rr], g2w[32 + rr], t1);
    }
    float mx = fmaxf(t0, t1);
    float e0 = expf(t0 - mx), e1 = expf(t1 - mx);
    float inv = 1.f / (e0 + e1);
    wgate[t * 2 + 0] = e0 * inv;
    wgate[t * 2 + 1] = e1 * inv;
  }
}

__device__ __forceinline__ float bf2f(unsigned short u) {
  return __uint_as_float(((unsigned)u) << 16);
}

// one block per (b, y, x-half): 128-channel x 128-pixel tile.
// attn[o,p] = fuse_b[o] + sum_c Wt[c,o]*a[c,p];  out = x*(0.5+0.5*attn)
__global__ __launch_bounds__(256) void fuse_kernel(
    const float* __restrict__ x, const __hip_bfloat16* __restrict__ hbuf,
    const __hip_bfloat16* __restrict__ vbuf, const float* __restrict__ fuse_w,
    const float* __restrict__ fuse_b, const float* __restrict__ wgate,
    float* __restrict__ out) {
  __shared__ unsigned short aS[128 * 128];  // a[c][p] bf16
  __shared__ unsigned short wS[128 * 128];  // Wt[c][o] bf16, o column swizzled
  int bid = blockIdx.x;        // (b*256 + y)*2 + half
  int half = bid & 1;
  int y = (bid >> 1) & 255;
  int b = bid >> 9;
  int t = threadIdx.x;
  float wh = wgate[b * 2], wv = wgate[b * 2 + 1];

  // stage Wt (swizzled column: col = (o + 8*(c&15)) & 127 to dodge bank conflicts)
  for (int q = t; q < 16384; q += 256) {
    int o = q >> 7, cc = q & 127;
    int col = (o + 8 * (cc & 15)) & 127;
    wS[cc * 128 + col] = __bfloat16_as_ushort(__float2bfloat16(fuse_w[q]));
  }
  // stage a = wh*h + wv*v
  size_t base = (size_t)b * CCH * HW + (size_t)y * WID + (size_t)half * 128;
  for (int q = t; q < 16384; q += 256) {
    int cc = q >> 7, p = q & 127;
    size_t gi = base + (size_t)cc * HW + p;
    float hv = __bfloat162float(hbuf[gi]);
    float vv = __bfloat162float(vbuf[gi]);
    aS[cc * 128 + p] = __bfloat16_as_ushort(__float2bfloat16(fmaf(wh, hv, wv * vv)));
  }
  __syncthreads();

  int o0 = (t >> 4) * 8;
  int p0 = (t & 15) * 8;
  float acc[8][8];
#pragma unroll
  for (int i = 0; i < 8; ++i)
#pragma unroll
    for (int j = 0; j < 8; ++j) acc[i][j] = 0.f;

  for (int cc = 0; cc < 128; ++cc) {
    int wbase = cc * 128 + ((o0 + 8 * (cc & 15)) & 127);
    int abase = cc * 128 + p0;
    ushort4 w0 = *(const ushort4*)&wS[wbase];
    ushort4 w1 = *(const ushort4*)&wS[wbase + 4];
    ushort4 a0 = *(const ushort4*)&aS[abase];
    ushort4 a1 = *(const ushort4*)&aS[abase + 4];
    float wr[8] = {bf2f(w0.x), bf2f(w0.y), bf2f(w0.z), bf2f(w0.w),
                   bf2f(w1.x), bf2f(w1.y), bf2f(w1.z), bf2f(w1.w)};
    float ar[8] = {bf2f(a0.x), bf2f(a0.y), bf2f(a0.z), bf2f(a0.w),
                   bf2f(a1.x), bf2f(a1.y), bf2f(a1.z), bf2f(a1.w)};
#pragma unroll
    for (int i = 0; i < 8; ++i)
#pragma unroll
      for (int j = 0; j < 8; ++j) acc[i][j] = fmaf(wr[i], ar[j], acc[i][j]);
  }

#pragma unroll
  for (int i = 0; i < 8; ++i) {
    int o = o0 + i;
    float fb = fuse_b[o];
    size_t gb = base + (size_t)o * HW + p0;
#pragma unroll
    for (int j = 0; j < 8; ++j) {
      float attn = fb + acc[i][j];
      float xv = x[gb + j];
      out[gb + j] = xv * fmaf(0.5f, attn, 0.5f);
    }
  }
}

extern "C" void kernel_launch(void* const* d_in, const int* in_sizes, int n_in,
                              void* d_out, int out_size, void* d_ws, size_t ws_size,
                              hipStream_t stream) {
  const float* x      = (const float*)d_in[0];
  const float* h1w    = (const float*)d_in[1];
  const float* h2w    = (const float*)d_in[2];
  const float* v1w    = (const float*)d_in[3];
  const float* v2w    = (const float*)d_in[4];
  const float* g1w    = (const float*)d_in[5];
  const float* g2w    = (const float*)d_in[6];
  const float* g2b    = (const float*)d_in[7];
  const float* fusew  = (const float*)d_in[8];
  const float* fuseb  = (const float*)d_in[9];
  float* out = (float*)d_out;

  float* sums  = (float*)d_ws;       // sum_h(512), sum_v(512), wgate(8)
  float* sum_h = sums;
  float* sum_v = sums + 512;
  float* wgate = sums + 1024;
  __hip_bfloat16* hbuf = (__hip_bfloat16*)((char*)d_ws + 32768);
  __hip_bfloat16* vbuf = hbuf + (size_t)4 * CCH * HW;

  prep_kernel<<<1, 256, 0, stream>>>(sums);
  convh_kernel<<<4 * CCH * 16, 256, 0, stream>>>(x, h1w, h2w, hbuf, sum_h);
  convv_kernel<<<4 * CCH * 2, 256, 0, stream>>>(x, v1w, v2w, vbuf, sum_v);
  gate_kernel<<<1, 128, 0, stream>>>(sum_h, sum_v, g1w, g2w, g2b, wgate);
  fuse_kernel<<<4 * HGT * 2, 256, 0, stream>>>(x, hbuf, vbuf, fusew, fuseb, wgate, out);
}

// Round 4
// 428.175 us; speedup vs baseline: 1.8490x; 1.2122x over previous
//
#include <hip/hip_runtime.h>
#include <hip/hip_bf16.h>

#define CCH 128
#define HGT 256
#define WID 256
#define HW  65536

typedef __attribute__((ext_vector_type(8))) short short8;
typedef __attribute__((ext_vector_type(4))) float floatx4;

// ws layout:
//   floats [0,512)    sum_h (4*128)
//   floats [512,1024) sum_v
//   floats [1024,1032) wgate (4*2)
//   byte 32768:       hbuf bf16 (4*128*65536)
//   then              vbuf bf16
// total ws needed = 32768 + 2*67108864 = 134,250,496 bytes

__global__ __launch_bounds__(256) void prep_kernel(float* __restrict__ sums) {
  int t = threadIdx.x;
  for (int i = t; i < 1032; i += 256) sums[i] = 0.f;  // sum_h, sum_v, wgate
}

// one block per (b,c,ytile16): exact two-stage horizontal conv on a 16-row tile.
__global__ __launch_bounds__(256) void convh_kernel(
    const float* __restrict__ x, const float* __restrict__ h1w,
    const float* __restrict__ h2w,
    __hip_bfloat16* __restrict__ hbuf, float* __restrict__ sum_h) {
  __shared__ float xr[16 * 260];
  __shared__ float tmp[16 * 276];
  __shared__ float red[4];
  int bid = blockIdx.x;          // (b*C + c)*16 + ytile
  int y0 = (bid & 15) * 16;
  int bc = bid >> 4;
  int c = bc & (CCH - 1);
  int t = threadIdx.x;
  int rowg = t >> 6;             // 0..3 (wave id)
  int c4 = (t & 63) * 4;

  if (t < 64) {
    int r = t >> 2, k = t & 3;
    int col = (k < 2) ? k : (256 + k);
    xr[r * 260 + col] = 0.f;
  }
  for (int i = t; i < 288; i += 256) {
    int r = i / 18, k = i - r * 18;
    int col = (k < 9) ? k : (256 + k);
    tmp[r * 276 + col] = 0.f;
  }

  const float* xg = x + (size_t)bc * HW + (size_t)y0 * WID;
#pragma unroll
  for (int k = 0; k < 4; ++k) {
    int r = 4 * k + rowg;
    float4 v = *(const float4*)(xg + (size_t)r * WID + c4);
    *(float2*)&xr[r * 260 + 2 + c4] = make_float2(v.x, v.y);
    *(float2*)&xr[r * 260 + 4 + c4] = make_float2(v.z, v.w);
  }
  float h1c[5], h2c[7];
#pragma unroll
  for (int i = 0; i < 5; ++i) h1c[i] = h1w[c * 5 + i];
#pragma unroll
  for (int j = 0; j < 7; ++j) h2c[j] = h2w[c * 7 + j];
  __syncthreads();

#pragma unroll
  for (int r = 0; r < 16; ++r) {
    float s1 = 0.f;
#pragma unroll
    for (int i = 0; i < 5; ++i) s1 = fmaf(xr[r * 260 + t + i], h1c[i], s1);
    tmp[r * 276 + 9 + t] = s1;
  }
  __syncthreads();

  __hip_bfloat16* hg = hbuf + (size_t)bc * HW + (size_t)y0 * WID + t;
  float acc = 0.f;
#pragma unroll
  for (int r = 0; r < 16; ++r) {
    float s = 0.f;
#pragma unroll
    for (int j = 0; j < 7; ++j) s = fmaf(tmp[r * 276 + t + 3 * j], h2c[j], s);
    hg[(size_t)r * WID] = __float2bfloat16(s);
    acc += s;
  }
#pragma unroll
  for (int off = 32; off > 0; off >>= 1) acc += __shfl_down(acc, off);
  if ((t & 63) == 0) red[t >> 6] = acc;
  __syncthreads();
  if (t == 0) atomicAdd(&sum_h[bc], red[0] + red[1] + red[2] + red[3]);
}

// one block per (b,c,y-half): exact two-stage vertical conv, register windows.
__global__ __launch_bounds__(256) void convv_kernel(
    const float* __restrict__ x, const float* __restrict__ v1w,
    const float* __restrict__ v2w,
    __hip_bfloat16* __restrict__ vbuf, float* __restrict__ sum_v) {
  int bid = blockIdx.x;        // (b*C + c)*2 + half
  int half = bid & 1;
  int bc = bid >> 1;
  int c = bc & (CCH - 1);
  int t = threadIdx.x;         // column
  int y0 = half * 128;
  const float* xp = x + (size_t)bc * HW;
  float v1c[5], v2c[7];
#pragma unroll
  for (int i = 0; i < 5; ++i) v1c[i] = v1w[c * 5 + i];
#pragma unroll
  for (int j = 0; j < 7; ++j) v2c[j] = v2w[c * 7 + j];

  float xloc[23];
#pragma unroll
  for (int m = 0; m < 23; ++m) {
    int yy = y0 - 11 + m;
    xloc[m] = (yy >= 0 && yy < HGT) ? xp[(size_t)yy * WID + t] : 0.f;
  }
  float s1w[19];
#pragma unroll
  for (int m = 0; m < 19; ++m) {
    int q = y0 - 9 + m;
    float v = 0.f;
    if (q >= 0 && q < HGT) {
#pragma unroll
      for (int i = 0; i < 5; ++i) v = fmaf(xloc[m + i], v1c[i], v);
    }
    s1w[m] = v;
  }
  float xw[5];
#pragma unroll
  for (int i = 0; i < 5; ++i) {
    int yy = y0 + 8 + i;
    xw[i] = (yy >= 0 && yy < HGT) ? xp[(size_t)yy * WID + t] : 0.f;
  }

  __hip_bfloat16* vp = vbuf + (size_t)bc * HW;
  float acc = 0.f;
  for (int y = y0; y < y0 + 128; ++y) {
    float s = 0.f;
#pragma unroll
    for (int j = 0; j < 7; ++j) s = fmaf(s1w[3 * j], v2c[j], s);
    vp[(size_t)y * WID + t] = __float2bfloat16(s);
    acc += s;
#pragma unroll
    for (int m = 0; m < 18; ++m) s1w[m] = s1w[m + 1];
    int q = y + 10;
    float ns = 0.f;
    if (q < HGT) {
#pragma unroll
      for (int i = 0; i < 5; ++i) ns = fmaf(xw[i], v1c[i], ns);
    }
    s1w[18] = ns;
#pragma unroll
    for (int i = 0; i < 4; ++i) xw[i] = xw[i + 1];
    int yy = y + 13;
    xw[4] = (yy < HGT) ? xp[(size_t)yy * WID + t] : 0.f;
  }
  __shared__ float red[4];
#pragma unroll
  for (int off = 32; off > 0; off >>= 1) acc += __shfl_down(acc, off);
  if ((t & 63) == 0) red[t >> 6] = acc;
  __syncthreads();
  if (t == 0) atomicAdd(&sum_v[bc], red[0] + red[1] + red[2] + red[3]);
}

// single block: pooled -> g1 -> SiLU -> g2 -> softmax
__global__ __launch_bounds__(128) void gate_kernel(
    const float* __restrict__ sum_h, const float* __restrict__ sum_v,
    const float* __restrict__ g1w, const float* __restrict__ g2w,
    const float* __restrict__ g2b, float* __restrict__ wgate) {
  int t = threadIdx.x;
  __shared__ float gs[4][32];
  int b = t >> 5, r = t & 31;
  {
    float acc = 0.f;
    const float inv = 1.f / 65536.f;
    for (int k = 0; k < 128; ++k)
      acc = fmaf(sum_h[b * 128 + k] * inv, g1w[r * 256 + k], acc);
    for (int k = 0; k < 128; ++k)
      acc = fmaf(sum_v[b * 128 + k] * inv, g1w[r * 256 + 128 + k], acc);
    float sig = 1.f / (1.f + expf(-acc));
    gs[b][r] = acc * sig;
  }
  __syncthreads();
  if (t < 4) {
    float t0 = g2b[0], t1 = g2b[1];
    for (int rr = 0; rr < 32; ++rr) {
      t0 = fmaf(gs[t][rr], g2w[rr], t0);
      t1 = fmaf(gs[t][rr], g2w[32 + rr], t1);
    }
    float mx = fmaxf(t0, t1);
    float e0 = expf(t0 - mx), e1 = expf(t1 - mx);
    float inv = 1.f / (e0 + e1);
    wgate[t * 2 + 0] = e0 * inv;
    wgate[t * 2 + 1] = e1 * inv;
  }
}

__device__ __forceinline__ float bf2f(unsigned short u) {
  return __uint_as_float(((unsigned)u) << 16);
}
__device__ __forceinline__ short f2bfs(float f) {
  return (short)__bfloat16_as_ushort(__float2bfloat16(f));
}

// MFMA fuse: one block per (b, y, half) = 128 o x 128 p, K = 128 c.
// attn = W x a, a = wh*h + wv*v staged in LDS as aT[p][c'] with swizzle
// c' = (c + 8*((p>>3)&15)) & 127 so B-fragments are single ds_read_b128.
// W A-fragments held in registers (2 m-tiles x 4 k-tiles per wave).
__global__ __launch_bounds__(256, 4) void fuse_kernel(
    const float* __restrict__ x, const __hip_bfloat16* __restrict__ hbuf,
    const __hip_bfloat16* __restrict__ vbuf, const float* __restrict__ fuse_w,
    const float* __restrict__ fuse_b, const float* __restrict__ wgate,
    float* __restrict__ out) {
  __shared__ unsigned short aT[128 * 128];  // [p][c'] bf16, 32 KB
  int bid = blockIdx.x;        // (b*256 + y)*2 + half
  int half = bid & 1;
  int y = (bid >> 1) & 255;
  int b = bid >> 9;
  int t = threadIdx.x;
  int w = t >> 6, lane = t & 63;
  int quad = lane >> 4, n16 = lane & 15;
  float wh = wgate[b * 2], wv = wgate[b * 2 + 1];

  // A-fragments of W: wave w owns o in [32w, 32w+32)
  // A[m=lane&15][k=quad*8+j]: o = mt*16 + n16, c = kt*32 + quad*8 + j
  short8 wf[2][4];
#pragma unroll
  for (int mi = 0; mi < 2; ++mi) {
    int o = (2 * w + mi) * 16 + n16;
#pragma unroll
    for (int kt = 0; kt < 4; ++kt) {
      const float* wp = fuse_w + o * 128 + kt * 32 + quad * 8;
      float4 f0 = *(const float4*)wp;
      float4 f1 = *(const float4*)(wp + 4);
      short8 s;
      s[0] = f2bfs(f0.x); s[1] = f2bfs(f0.y); s[2] = f2bfs(f0.z); s[3] = f2bfs(f0.w);
      s[4] = f2bfs(f1.x); s[5] = f2bfs(f1.y); s[6] = f2bfs(f1.z); s[7] = f2bfs(f1.w);
      wf[mi][kt] = s;
    }
  }

  // stage a: thread reads (c = cpass*16 + t>>4, pixels p0..p0+7), p0=(t&15)*8
  size_t base = (size_t)(b * CCH) * HW + (size_t)y * WID + half * 128;
  const unsigned short* hb = (const unsigned short*)hbuf;
  const unsigned short* vb = (const unsigned short*)vbuf;
  int cth = t >> 4;
  int p0 = (t & 15) * 8;
  int swz = 8 * (t & 15);      // 8*((p>>3)&15), constant over the thread's 8 p
#pragma unroll
  for (int cpass = 0; cpass < 8; ++cpass) {
    int c = cpass * 16 + cth;
    size_t gi = base + (size_t)c * HW + p0;
    ushort4 h0 = *(const ushort4*)(hb + gi);
    ushort4 h1 = *(const ushort4*)(hb + gi + 4);
    ushort4 v0 = *(const ushort4*)(vb + gi);
    ushort4 v1 = *(const ushort4*)(vb + gi + 4);
    int cpr = (c + swz) & 127;
    float a0 = fmaf(wh, bf2f(h0.x), wv * bf2f(v0.x));
    float a1 = fmaf(wh, bf2f(h0.y), wv * bf2f(v0.y));
    float a2 = fmaf(wh, bf2f(h0.z), wv * bf2f(v0.z));
    float a3 = fmaf(wh, bf2f(h0.w), wv * bf2f(v0.w));
    float a4 = fmaf(wh, bf2f(h1.x), wv * bf2f(v1.x));
    float a5 = fmaf(wh, bf2f(h1.y), wv * bf2f(v1.y));
    float a6 = fmaf(wh, bf2f(h1.z), wv * bf2f(v1.z));
    float a7 = fmaf(wh, bf2f(h1.w), wv * bf2f(v1.w));
    aT[(p0 + 0) * 128 + cpr] = (unsigned short)f2bfs(a0);
    aT[(p0 + 1) * 128 + cpr] = (unsigned short)f2bfs(a1);
    aT[(p0 + 2) * 128 + cpr] = (unsigned short)f2bfs(a2);
    aT[(p0 + 3) * 128 + cpr] = (unsigned short)f2bfs(a3);
    aT[(p0 + 4) * 128 + cpr] = (unsigned short)f2bfs(a4);
    aT[(p0 + 5) * 128 + cpr] = (unsigned short)f2bfs(a5);
    aT[(p0 + 6) * 128 + cpr] = (unsigned short)f2bfs(a6);
    aT[(p0 + 7) * 128 + cpr] = (unsigned short)f2bfs(a7);
  }
  __syncthreads();

  // MFMA: acc[mi][nt], B[k=quad*8+j][n=n16] from aT[nt*16+n16][...]
  floatx4 acc[2][8];
#pragma unroll
  for (int mi = 0; mi < 2; ++mi)
#pragma unroll
    for (int nt = 0; nt < 8; ++nt) acc[mi][nt] = (floatx4)0.f;

#pragma unroll
  for (int kt = 0; kt < 4; ++kt) {
#pragma unroll
    for (int nt = 0; nt < 8; ++nt) {
      int p = nt * 16 + n16;
      int cpr = (kt * 32 + quad * 8 + 8 * ((p >> 3) & 15)) & 127;
      short8 bfr = *(const short8*)&aT[p * 128 + cpr];
      acc[0][nt] = __builtin_amdgcn_mfma_f32_16x16x32_bf16(wf[0][kt], bfr, acc[0][nt], 0, 0, 0);
      acc[1][nt] = __builtin_amdgcn_mfma_f32_16x16x32_bf16(wf[1][kt], bfr, acc[1][nt], 0, 0, 0);
    }
  }

  // epilogue: D[m][n]: o = mt*16 + quad*4 + r, p = nt*16 + n16
#pragma unroll
  for (int mi = 0; mi < 2; ++mi) {
    int ob = (2 * w + mi) * 16 + quad * 4;
#pragma unroll
    for (int r = 0; r < 4; ++r) {
      int o = ob + r;
      float fb = fuse_b[o];
      size_t gb = base + (size_t)o * HW + n16;
#pragma unroll
      for (int nt = 0; nt < 8; ++nt) {
        size_t gi = gb + nt * 16;
        float attn = fb + acc[mi][nt][r];
        out[gi] = x[gi] * fmaf(0.5f, attn, 0.5f);
      }
    }
  }
}

extern "C" void kernel_launch(void* const* d_in, const int* in_sizes, int n_in,
                              void* d_out, int out_size, void* d_ws, size_t ws_size,
                              hipStream_t stream) {
  const float* x      = (const float*)d_in[0];
  const float* h1w    = (const float*)d_in[1];
  const float* h2w    = (const float*)d_in[2];
  const float* v1w    = (const float*)d_in[3];
  const float* v2w    = (const float*)d_in[4];
  const float* g1w    = (const float*)d_in[5];
  const float* g2w    = (const float*)d_in[6];
  const float* g2b    = (const float*)d_in[7];
  const float* fusew  = (const float*)d_in[8];
  const float* fuseb  = (const float*)d_in[9];
  float* out = (float*)d_out;

  float* sums  = (float*)d_ws;       // sum_h(512), sum_v(512), wgate(8)
  float* sum_h = sums;
  float* sum_v = sums + 512;
  float* wgate = sums + 1024;
  __hip_bfloat16* hbuf = (__hip_bfloat16*)((char*)d_ws + 32768);
  __hip_bfloat16* vbuf = hbuf + (size_t)4 * CCH * HW;

  prep_kernel<<<1, 256, 0, stream>>>(sums);
  convh_kernel<<<4 * CCH * 16, 256, 0, stream>>>(x, h1w, h2w, hbuf, sum_h);
  convv_kernel<<<4 * CCH * 2, 256, 0, stream>>>(x, v1w, v2w, vbuf, sum_v);
  gate_kernel<<<1, 128, 0, stream>>>(sum_h, sum_v, g1w, g2w, g2b, wgate);
  fuse_kernel<<<4 * HGT * 2, 256, 0, stream>>>(x, hbuf, vbuf, fusew, fuseb, wgate, out);
}